// Round 10
// baseline (498.897 us; speedup 1.0000x reference)
//
#include <hip/hip_runtime.h>
#include <hip/hip_bf16.h>
#include <math.h>

// ODE Euler solver — R13: weights direct-to-register + unchunked H.
// R12 lesson: per-wave TOTAL (arch+acc) budget at 2 waves/SIMD is 256;
// W1-resident (128) blew it -> spill. R11 lesson (recount): its LDS pipe was
// ~saturated (192 ds_read_b128/wave/step + 512KB DMA writes) -> R11 = its
// structure's LDS roofline. This round cuts LDS traffic instead:
//  * Weight tiles are WAVE-PRIVATE -> the global->LDS->reg ring round-trip
//    is pure overhead (m151's gload_lds win needs cross-wave reuse). Stream
//    W1/W2 global->reg, 2-deep pipeline (~32 regs in flight). Removes all
//    weight ds_reads AND all DMA LDS-writes. No hand vmcnt needed.
//  * Unchunked H: uB = full u (64KB, fits once ring is gone). MM1 = 4 mt/wave
//    -> each zB read feeds 4 MFMAs (B-read duplication halved); 2 barriers
//    per step instead of 4.
//  * kt=0 weight frags resident (24 regs, step-invariant) -> no exposed
//    load latency at phase entry (asm"memory" barrier blocks load hoisting).
// Reg ledger: acc 96 (AGPR) + resident 24 + stream 32 + bias 24 + work ~60
// ~= 235 <= 250. Spill tripwire: FETCH >> 100MB.

using bf16x8 = __attribute__((ext_vector_type(8))) short;   // 8 bf16
using f32x4  = __attribute__((ext_vector_type(4))) float;   // 4 fp32 acc

constexpr int Bb = 64, Cc = 256, Tt = 64, Vv = 25, Hh = 512;
constexpr int TV = Tt * Vv;              // 1600
constexpr int MAXCH = Bb * (Tt - 1);     // 4032
constexpr int NGRID = 2496;              // >= worst-case n1+npair
constexpr int NTMAX = 4;                 // LDS stride in n-tiles

__device__ __forceinline__ short f2bf(float x) {
  union { float f; unsigned u; } v; v.f = x;
  unsigned r = v.u + 0x7FFFu + ((v.u >> 16) & 1u);
  return (short)(r >> 16);
}
__device__ __forceinline__ float fast_tanh(float x) {
  float e = __expf(2.f * x);
  return 1.f - 2.f * __builtin_amdgcn_rcpf(e + 1.f);
}
// lgkm-only barrier: LDS deps drained, global loads/stores stay in flight.
__device__ __forceinline__ void bar_lds() {
  asm volatile("s_waitcnt lgkmcnt(0)" ::: "memory");
  __builtin_amdgcn_s_barrier();
  asm volatile("" ::: "memory");
}

// ---- fused prepack (blocks 0..1023) + plan (block 1024) ----
// A-frag (16x16x32): lane holds A[m=lane&15][k=(lane>>4)*8+j].
// a1p: A=W1^T (M=H: 32 mt, K=C: 8 kt):  idx ((kt*32+mt)*64+lane)*8+j
// a2p: A=W2^T (M=C: 16 mt, K=H: 16 kt): idx ((kt*16+mt)*64+lane)*8+j
__global__ void prep_kernel(const float* __restrict__ W1,
                            const float* __restrict__ W2,
                            const float* __restrict__ tf,
                            short* __restrict__ a1p,
                            short* __restrict__ a2p,
                            int* __restrict__ sorted,
                            int* __restrict__ hdr) {
  if (blockIdx.x < 1024) {
    int idx = blockIdx.x * 256 + threadIdx.x;
    if (idx < 131072) {
      int j = idx & 7, lane = (idx >> 3) & 63, mt = (idx >> 9) & 31, kt = idx >> 14;
      int h = mt * 16 + (lane & 15);
      int c = kt * 32 + (lane >> 4) * 8 + j;
      a1p[idx] = f2bf(W1[c * Hh + h]);
    } else {
      int i2 = idx - 131072;
      int j = i2 & 7, lane = (i2 >> 3) & 63, mt = (i2 >> 9) & 15, kt = i2 >> 13;
      int cm = mt * 16 + (lane & 15);
      int hk = kt * 32 + (lane >> 4) * 8 + j;
      a2p[i2] = f2bf(W2[hk * Cc + cm]);
    }
    return;
  }
  __shared__ int cnt[64];
  __shared__ int ofs[64];
  int tid = threadIdx.x;
  if (tid < 64) cnt[tid] = 0;
  for (int i = tid; i < MAXCH; i += 256) sorted[i] = 0;
  __syncthreads();
  if (tid < Bb) {
    int b = tid, prev = 0;
    for (int t = 1; t <= 62; t++)
      if (tf[t * Bb + b] >= 0.5f) { atomicAdd(&cnt[t - prev], 1); prev = t; }
    atomicAdd(&cnt[63 - prev], 1);
  }
  __syncthreads();
  if (tid == 0) {
    int acc = 0;
    for (int l = 63; l >= 1; l--) { ofs[l] = acc; acc += cnt[l]; }
    int n1 = 0;
    for (int l = 5; l <= 63; l++) n1 += cnt[l];
    hdr[0] = n1;                      // solos (len>=5)
    hdr[1] = (acc - n1 + 1) >> 1;     // pairs covering the rest
    hdr[2] = acc; hdr[3] = 0;
  }
  __syncthreads();
  if (tid < Bb) {
    int b = tid, prev = 0;
    for (int t = 1; t <= 62; t++) {
      if (tf[t * Bb + b] >= 0.5f) {
        int len = t - prev;
        int p = atomicAdd(&ofs[len], 1);
        sorted[p] = b | (prev << 6) | (len << 12);
        prev = t;
      }
    }
    int len = 63 - prev;
    int p = atomicAdd(&ofs[len], 1);
    sorted[p] = b | (prev << 6) | (len << 12);
  }
}

// LDS B-frag order (stride NTMAX):
// elem(k,n) at ((ktile*NTMAX + nt)*64 + (n&15) + 16*((k&31)>>3))*8 + (k&7)
template<int NCH>
__device__ __forceinline__ void run_group(
    int start,
    const float* __restrict__ hsrc, const float* __restrict__ b1,
    const float* __restrict__ b2,   const short* __restrict__ a1p,
    const short* __restrict__ a2p,  const int* __restrict__ sorted,
    float* __restrict__ out, short* __restrict__ zB, short* __restrict__ uB) {
  constexpr int NTA = NCH * 2;                  // n-tiles (16 cols each)
  const int tid  = threadIdx.x;
  const int lane = tid & 63;
  const int w    = tid >> 6;                    // 0..7
  const int m16  = lane & 15;
  const int quad = lane >> 4;

  int meta[NCH], len[NCH], sbase[NCH], t0s[NCH];
  #pragma unroll
  for (int j = 0; j < NCH; j++) {
    meta[j]  = sorted[start + j];               // block-uniform -> s_load
    len[j]   = (meta[j] >> 12) & 63;
    t0s[j]   = (meta[j] >> 6) & 63;
    sbase[j] = (meta[j] & 63) * Cc * TV + t0s[j] * Vv;
  }
  const int maxlen = len[0];                    // sorted desc

  // Weight fragment loaders (global -> regs, wave-private slices).
  // W1: wave owns mt = w*4 .. w*4+3 (of 32).  W2: mt = w*2, w*2+1 (of 16).
  auto LDW1 = [&](int kt, bf16x8 (&f)[4]) {
    const short* ab = a1p + ((kt * 32 + w * 4) * 64 + lane) * 8;
    f[0] = *(const bf16x8*)ab;
    f[1] = *(const bf16x8*)(ab + 512);
    f[2] = *(const bf16x8*)(ab + 1024);
    f[3] = *(const bf16x8*)(ab + 1536);
  };
  auto LDW2 = [&](int kt, bf16x8 (&f)[2]) {
    const short* ab = a2p + ((kt * 16 + w * 2) * 64 + lane) * 8;
    f[0] = *(const bf16x8*)ab;
    f[1] = *(const bf16x8*)(ab + 512);
  };

  f32x4 acc2[2][NTA];                           // fp32 master state (C-dim: 2 mt/wave)

  // ---- init: z0 = h[b,:,t0,:]; write zB in B-frag order ----
  #pragma unroll
  for (int i = 0; i < 2; i++) {
    const int cbase = (w * 2 + i) * 16 + quad * 4;    // 0..255, mult of 4
    const int ktz = cbase >> 5;
    const int gq  = (cbase >> 3) & 3;
    const int j0  = cbase & 7;
    #pragma unroll
    for (int nt = 0; nt < NTA; nt++) {
      const int j  = nt >> 1;
      const int v  = (nt & 1) * 16 + m16;
      const bool valid = (len[j] > 0) && (v < Vv);
      const int hb = sbase[j] + cbase * TV + v;
      f32x4 z;
      #pragma unroll
      for (int r = 0; r < 4; r++)
        z[r] = valid ? __builtin_nontemporal_load(&hsrc[hb + r * TV]) : 0.f;
      acc2[i][nt] = z;
      short4 zh;
      zh.x = f2bf(z[0]); zh.y = f2bf(z[1]); zh.z = f2bf(z[2]); zh.w = f2bf(z[3]);
      *(short4*)&zB[((ktz * NTMAX + nt) * 64 + m16 + 16 * gq) * 8 + j0] = zh;
      if (valid && t0s[j] == 0) {
        #pragma unroll
        for (int r = 0; r < 4; r++) out[hb + r * TV] = z[r];
      }
    }
  }

  // kt=0 weight frags resident (step-invariant, 24 regs): phase entry has
  // zero exposed load latency (the "memory" barrier blocks hoisting).
  bf16x8 w1k0[4], w2k0[2];
  LDW1(0, w1k0);
  LDW2(0, w2k0);

  // step-invariant biases in registers
  f32x4 b2v[2];                 // C-dim (2 mt/wave)
  f32x4 b1v[4];                 // H-dim (4 mt/wave)
  #pragma unroll
  for (int i = 0; i < 2; i++) {
    const float4 t = *(const float4*)(b2 + (w * 2 + i) * 16 + quad * 4);
    b2v[i] = (f32x4){t.x, t.y, t.z, t.w};
  }
  #pragma unroll
  for (int i = 0; i < 4; i++) {
    const float4 u = *(const float4*)(b1 + (w * 4 + i) * 16 + quad * 4);
    b1v[i] = (f32x4){u.x, u.y, u.z, u.w};
  }

  bar_lds();                    // zB visible

  for (int s = 0; s < maxlen; s++) {
    // ---- bias(b2) into master state ----
    #pragma unroll
    for (int i = 0; i < 2; i++)
      #pragma unroll
      for (int nt = 0; nt < NTA; nt++) {
        acc2[i][nt][0] += b2v[i][0]; acc2[i][nt][1] += b2v[i][1];
        acc2[i][nt][2] += b2v[i][2]; acc2[i][nt][3] += b2v[i][3];
      }

    // ---- MM1: u_pre = W1^T z (K=256: 8 kt; 4 mt/wave; W1 streamed) ----
    f32x4 acc1[4][NTA];
    #pragma unroll
    for (int i = 0; i < 4; i++)
      #pragma unroll
      for (int nt = 0; nt < NTA; nt++) acc1[i][nt] = (f32x4){0.f, 0.f, 0.f, 0.f};

    {
      bf16x8 nA[4];
      LDW1(1, nA);
      // kt = 0 from resident regs
      #pragma unroll
      for (int nt = 0; nt < NTA; nt++) {
        bf16x8 bz = *(const bf16x8*)&zB[((0 * NTMAX + nt) * 64 + lane) * 8];
        acc1[0][nt] = __builtin_amdgcn_mfma_f32_16x16x32_bf16(w1k0[0], bz, acc1[0][nt], 0, 0, 0);
        acc1[1][nt] = __builtin_amdgcn_mfma_f32_16x16x32_bf16(w1k0[1], bz, acc1[1][nt], 0, 0, 0);
        acc1[2][nt] = __builtin_amdgcn_mfma_f32_16x16x32_bf16(w1k0[2], bz, acc1[2][nt], 0, 0, 0);
        acc1[3][nt] = __builtin_amdgcn_mfma_f32_16x16x32_bf16(w1k0[3], bz, acc1[3][nt], 0, 0, 0);
      }
      #pragma unroll
      for (int kt = 1; kt < 8; kt++) {
        bf16x8 cA[4];
        #pragma unroll
        for (int i = 0; i < 4; i++) cA[i] = nA[i];
        if (kt < 7) LDW1(kt + 1, nA);
        #pragma unroll
        for (int nt = 0; nt < NTA; nt++) {
          bf16x8 bz = *(const bf16x8*)&zB[((kt * NTMAX + nt) * 64 + lane) * 8];
          acc1[0][nt] = __builtin_amdgcn_mfma_f32_16x16x32_bf16(cA[0], bz, acc1[0][nt], 0, 0, 0);
          acc1[1][nt] = __builtin_amdgcn_mfma_f32_16x16x32_bf16(cA[1], bz, acc1[1][nt], 0, 0, 0);
          acc1[2][nt] = __builtin_amdgcn_mfma_f32_16x16x32_bf16(cA[2], bz, acc1[2][nt], 0, 0, 0);
          acc1[3][nt] = __builtin_amdgcn_mfma_f32_16x16x32_bf16(cA[3], bz, acc1[3][nt], 0, 0, 0);
        }
      }
    }

    // ---- u epilogue -> uB (full H, B-frag order: 16 ktiles) ----
    #pragma unroll
    for (int i = 0; i < 4; i++) {
      const int hl  = (w * 4 + i) * 16 + quad * 4;   // 0..511
      const int ktl = hl >> 5;
      const int gq  = (hl >> 3) & 3;
      const int j0  = hl & 7;
      #pragma unroll
      for (int nt = 0; nt < NTA; nt++) {
        short4 up;
        up.x = f2bf(fast_tanh(acc1[i][nt][0] + b1v[i][0]));
        up.y = f2bf(fast_tanh(acc1[i][nt][1] + b1v[i][1]));
        up.z = f2bf(fast_tanh(acc1[i][nt][2] + b1v[i][2]));
        up.w = f2bf(fast_tanh(acc1[i][nt][3] + b1v[i][3]));
        *(short4*)&uB[((ktl * NTMAX + nt) * 64 + m16 + 16 * gq) * 8 + j0] = up;
      }
    }

    bar_lds();   // A: uB visible (also: all zB reads of this step done)

    // ---- MM2: acc2 += W2^T u (K=512: 16 kt; 2 mt/wave; W2 streamed) ----
    {
      bf16x8 nA[2];
      LDW2(1, nA);
      #pragma unroll
      for (int nt = 0; nt < NTA; nt++) {
        bf16x8 bu = *(const bf16x8*)&uB[((0 * NTMAX + nt) * 64 + lane) * 8];
        acc2[0][nt] = __builtin_amdgcn_mfma_f32_16x16x32_bf16(w2k0[0], bu, acc2[0][nt], 0, 0, 0);
        acc2[1][nt] = __builtin_amdgcn_mfma_f32_16x16x32_bf16(w2k0[1], bu, acc2[1][nt], 0, 0, 0);
      }
      #pragma unroll
      for (int kt = 1; kt < 16; kt++) {
        bf16x8 cA[2];
        cA[0] = nA[0]; cA[1] = nA[1];
        if (kt < 15) LDW2(kt + 1, nA);
        #pragma unroll
        for (int nt = 0; nt < NTA; nt++) {
          bf16x8 bu = *(const bf16x8*)&uB[((kt * NTMAX + nt) * 64 + lane) * 8];
          acc2[0][nt] = __builtin_amdgcn_mfma_f32_16x16x32_bf16(cA[0], bu, acc2[0][nt], 0, 0, 0);
          acc2[1][nt] = __builtin_amdgcn_mfma_f32_16x16x32_bf16(cA[1], bu, acc2[1][nt], 0, 0, 0);
        }
      }
    }

    // ---- z epilogue: refresh zB, store alive cols (plain L2 stores) ----
    #pragma unroll
    for (int i = 0; i < 2; i++) {
      const int cbase = (w * 2 + i) * 16 + quad * 4;
      const int ktz = cbase >> 5;
      const int gq  = (cbase >> 3) & 3;
      const int j0  = cbase & 7;
      #pragma unroll
      for (int nt = 0; nt < NTA; nt++) {
        short4 zh;
        zh.x = f2bf(acc2[i][nt][0]); zh.y = f2bf(acc2[i][nt][1]);
        zh.z = f2bf(acc2[i][nt][2]); zh.w = f2bf(acc2[i][nt][3]);
        *(short4*)&zB[((ktz * NTMAX + nt) * 64 + m16 + 16 * gq) * 8 + j0] = zh;
        const int v = (nt & 1) * 16 + m16;
        if (v < Vv && s < len[nt >> 1]) {
          const int o = sbase[nt >> 1] + cbase * TV + v + (s + 1) * Vv;
          out[o]          = acc2[i][nt][0];
          out[o + TV]     = acc2[i][nt][1];
          out[o + 2 * TV] = acc2[i][nt][2];
          out[o + 3 * TV] = acc2[i][nt][3];
        }
      }
    }
    bar_lds();   // D: zB ready for next step (also: all uB reads done)
  }
}

__global__ __launch_bounds__(512, 2) void group_kernel(
    const float* __restrict__ hsrc, const float* __restrict__ b1,
    const float* __restrict__ b2,   const short* __restrict__ a1p,
    const short* __restrict__ a2p,  const int* __restrict__ sorted,
    const int* __restrict__ hdr,    float* __restrict__ out) {
  __shared__ __align__(16) short zB[8 * NTMAX * 64 * 8];    // 32 KB (K=256)
  __shared__ __align__(16) short uB[16 * NTMAX * 64 * 8];   // 64 KB (K=512)

  const int n1 = hdr[0], npair = hdr[1];
  const int bi = blockIdx.x;
  if (bi < n1) {
    run_group<1>(bi, hsrc, b1, b2, a1p, a2p, sorted, out, zB, uB);
  } else if (bi < n1 + npair) {
    run_group<2>(n1 + (bi - n1) * 2, hsrc, b1, b2, a1p, a2p, sorted, out, zB, uB);
  }
}

extern "C" void kernel_launch(void* const* d_in, const int* in_sizes, int n_in,
                              void* d_out, int out_size, void* d_ws, size_t ws_size,
                              hipStream_t stream) {
  const float* h_ptr = (const float*)d_in[0];
  const float* W1    = (const float*)d_in[1];
  const float* b1    = (const float*)d_in[2];
  const float* W2    = (const float*)d_in[3];
  const float* b2    = (const float*)d_in[4];
  const float* tf    = (const float*)d_in[5];
  float* out = (float*)d_out;

  short* a1p  = (short*)d_ws;            // 256 KB
  short* a2p  = a1p + 131072;            // 256 KB
  int* sorted = (int*)(a2p + 131072);    // 16 KB
  int* hdr    = sorted + MAXCH;          // 16 B

  prep_kernel<<<1025, 256, 0, stream>>>(W1, W2, tf, a1p, a2p, sorted, hdr);
  group_kernel<<<NGRID, 512, 0, stream>>>(h_ptr, b1, b2, a1p, a2p, sorted, hdr, out);
}